// Round 1
// baseline (492.830 us; speedup 1.0000x reference)
//
#include <hip/hip_runtime.h>
#include <math.h>

#define M_TOT   16384      // B*N = 4*4096
#define F_DIM   768
#define C_DIM   64
#define P_DIM   8192
#define EPSN    1e-12f
#define NCHUNK  16
#define PCHUNK  (P_DIM / NCHUNK)   // 512
#define NEG_BIG (-3.402823466e38f)

// ---------------- Kernel A: cn = l2norm(codebook) rows ----------------
__global__ void k_norm_cb(const float* __restrict__ cb, float* __restrict__ cn) {
    int wv = threadIdx.x >> 6, lane = threadIdx.x & 63;
    int row = blockIdx.x * 4 + wv;
    float v = cb[(size_t)row * C_DIM + lane];
    float s = v * v;
    #pragma unroll
    for (int o = 32; o; o >>= 1) s += __shfl_xor(s, o, 64);
    float inv = 1.0f / fmaxf(sqrtf(s), EPSN);
    cn[(size_t)row * C_DIM + lane] = v * inv;
}

// ---------------- Kernel A2: w_outT[c][f] = w_out[f][c] ----------------
__global__ void k_transpose_wout(const float* __restrict__ w_out, float* __restrict__ wT) {
    int i = blockIdx.x * 256 + threadIdx.x;   // 49152 total
    int f = i >> 6, c = i & 63;
    wT[(size_t)c * F_DIM + f] = w_out[i];
}

// ---------------- Kernel B: zn = l2norm(z @ w_in^T) ----------------
// block = 256 thr (4 waves), 32 rows/block (8 rows/wave), K staged in LDS
#define B_ROWS 32
#define B_KCH  128
__global__ void k_proj(const float* __restrict__ z, const float* __restrict__ w_in,
                       float* __restrict__ zn) {
    __shared__ float lw[B_KCH][65];
    int wv = threadIdx.x >> 6, lane = threadIdx.x & 63;
    int m0 = blockIdx.x * B_ROWS + wv * 8;

    const float* zrow[8];
    #pragma unroll
    for (int r = 0; r < 8; ++r) {
        int mrow = __builtin_amdgcn_readfirstlane(m0 + r);
        zrow[r] = z + (size_t)mrow * F_DIM;
    }

    float acc[8];
    #pragma unroll
    for (int r = 0; r < 8; ++r) acc[r] = 0.0f;

    for (int k0 = 0; k0 < F_DIM; k0 += B_KCH) {
        // stage w_in[c][k0:k0+128] transposed -> lw[k][c]
        int c  = threadIdx.x >> 2;
        int kp = (threadIdx.x & 3) * 32;
        const float4* src = (const float4*)(w_in + (size_t)c * F_DIM + k0 + kp);
        #pragma unroll
        for (int j = 0; j < 8; ++j) {
            float4 w4 = src[j];
            int k = kp + j * 4;
            lw[k + 0][c] = w4.x; lw[k + 1][c] = w4.y;
            lw[k + 2][c] = w4.z; lw[k + 3][c] = w4.w;
        }
        __syncthreads();
        for (int k = 0; k < B_KCH; k += 4) {
            float w0 = lw[k][lane], w1 = lw[k + 1][lane];
            float w2 = lw[k + 2][lane], w3 = lw[k + 3][lane];
            #pragma unroll
            for (int r = 0; r < 8; ++r) {
                float4 zv = *(const float4*)(zrow[r] + k0 + k);
                acc[r] = fmaf(zv.x, w0, acc[r]);
                acc[r] = fmaf(zv.y, w1, acc[r]);
                acc[r] = fmaf(zv.z, w2, acc[r]);
                acc[r] = fmaf(zv.w, w3, acc[r]);
            }
        }
        __syncthreads();
    }
    #pragma unroll
    for (int r = 0; r < 8; ++r) {
        float s = acc[r] * acc[r];
        #pragma unroll
        for (int o = 32; o; o >>= 1) s += __shfl_xor(s, o, 64);
        float inv = 1.0f / fmaxf(sqrtf(s), EPSN);
        zn[(size_t)(m0 + r) * C_DIM + lane] = acc[r] * inv;
    }
}

// ---------------- Kernel C: fused sim + argmax over a P-chunk ----------------
// block = 64 threads (1 wave), lane = row. cn[p] loads are wave-uniform -> s_load.
__global__ void k_argmax(const float* __restrict__ zn, const float* __restrict__ cn,
                         float* __restrict__ pval, int* __restrict__ pidx) {
    int lane = threadIdx.x;
    int m = blockIdx.x * 64 + lane;
    int p0 = blockIdx.y * PCHUNK;

    float zr[64];
    #pragma unroll
    for (int j = 0; j < 16; ++j) {
        float4 v = *(const float4*)(zn + (size_t)m * C_DIM + j * 4);
        zr[4 * j] = v.x; zr[4 * j + 1] = v.y; zr[4 * j + 2] = v.z; zr[4 * j + 3] = v.w;
    }

    float best = NEG_BIG;
    int   bi   = 0;
    #pragma unroll 2
    for (int p = p0; p < p0 + PCHUNK; ++p) {
        const float4* cp = (const float4*)(cn + (size_t)p * C_DIM);
        float a0 = 0.f, a1 = 0.f, a2 = 0.f, a3 = 0.f;
        #pragma unroll
        for (int j = 0; j < 16; ++j) {
            float4 w = cp[j];
            a0 = fmaf(w.x, zr[4 * j + 0], a0);
            a1 = fmaf(w.y, zr[4 * j + 1], a1);
            a2 = fmaf(w.z, zr[4 * j + 2], a2);
            a3 = fmaf(w.w, zr[4 * j + 3], a3);
        }
        float s = (a0 + a1) + (a2 + a3);
        if (s > best) { best = s; bi = p; }   // strict > : lowest index wins ties
    }
    pval[(size_t)m * NCHUNK + blockIdx.y] = best;
    pidx[(size_t)m * NCHUNK + blockIdx.y] = bi;
}

// ---------------- Kernel C2: merge chunk partials -> idx ----------------
__global__ void k_merge(const float* __restrict__ pval, const int* __restrict__ pidx,
                        int* __restrict__ idx_i, float* __restrict__ idx_f) {
    int m = blockIdx.x * 256 + threadIdx.x;
    float best = NEG_BIG;
    int bi = 0;
    #pragma unroll
    for (int ch = 0; ch < NCHUNK; ++ch) {      // ascending chunk: lowest index wins ties
        float v = pval[(size_t)m * NCHUNK + ch];
        int   ii = pidx[(size_t)m * NCHUNK + ch];
        if (v > best) { best = v; bi = ii; }
    }
    idx_i[m] = bi;
    idx_f[m] = (float)bi;
}

// ---------------- Kernel D: out = codes @ w_outT ----------------
// block = 256 thr (4 waves); wave handles 32 rows at one 64-wide f-chunk.
#define D_ROWS 128
__global__ void k_out(const int* __restrict__ idx, const float* __restrict__ cn,
                      const float* __restrict__ wT, float* __restrict__ out) {
    int wv = threadIdx.x >> 6, lane = threadIdx.x & 63;
    int f  = blockIdx.y * 64 + lane;
    int m0 = blockIdx.x * D_ROWS + wv * 32;

    float wcol[64];
    #pragma unroll
    for (int c = 0; c < 64; ++c) wcol[c] = wT[(size_t)c * F_DIM + f];

    #pragma unroll 4
    for (int r = 0; r < 32; ++r) {
        int m = __builtin_amdgcn_readfirstlane(m0 + r);
        const float4* cp = (const float4*)(cn + (size_t)idx[m] * C_DIM);
        float acc = 0.f;
        #pragma unroll
        for (int j = 0; j < 16; ++j) {
            float4 cv = cp[j];
            acc = fmaf(cv.x, wcol[4 * j + 0], acc);
            acc = fmaf(cv.y, wcol[4 * j + 1], acc);
            acc = fmaf(cv.z, wcol[4 * j + 2], acc);
            acc = fmaf(cv.w, wcol[4 * j + 3], acc);
        }
        out[(size_t)m * F_DIM + f] = acc;
    }
}

// ---------------- Kernel E: per-block loss partials ----------------
__global__ void k_loss(const float* __restrict__ zn, const float* __restrict__ cn,
                       const int* __restrict__ idx, float* __restrict__ lossp) {
    __shared__ float wsum[4];
    int wv = threadIdx.x >> 6, lane = threadIdx.x & 63;
    int m = blockIdx.x * 4 + wv;
    int ci = idx[m];
    float zv = zn[(size_t)m * C_DIM + lane];
    float cv = cn[(size_t)ci * C_DIM + lane];
    float d = zv - cv;
    float s = d * d;
    #pragma unroll
    for (int o = 32; o; o >>= 1) s += __shfl_xor(s, o, 64);
    if (lane == 0) wsum[wv] = s;
    __syncthreads();
    if (threadIdx.x == 0) lossp[blockIdx.x] = (wsum[0] + wsum[1]) + (wsum[2] + wsum[3]);
}

// ---------------- Kernel F: finalize loss (deterministic) ----------------
__global__ void k_loss_final(const float* __restrict__ lossp, float* __restrict__ loss_out) {
    __shared__ float sh[256];
    float s = 0.f;
    for (int i = threadIdx.x; i < 4096; i += 256) s += lossp[i];
    sh[threadIdx.x] = s;
    __syncthreads();
    for (int o = 128; o; o >>= 1) {
        if (threadIdx.x < o) sh[threadIdx.x] += sh[threadIdx.x + o];
        __syncthreads();
    }
    if (threadIdx.x == 0)
        loss_out[0] = 1.25f * sh[0] / (float)(M_TOT * C_DIM);
}

extern "C" void kernel_launch(void* const* d_in, const int* in_sizes, int n_in,
                              void* d_out, int out_size, void* d_ws, size_t ws_size,
                              hipStream_t stream) {
    const float* z     = (const float*)d_in[0];
    const float* w_in  = (const float*)d_in[1];
    const float* w_out = (const float*)d_in[2];
    const float* cb    = (const float*)d_in[3];

    float* out    = (float*)d_out;                    // 16384*768
    float* lossO  = out + (size_t)M_TOT * F_DIM;      // 1
    float* idxO   = lossO + 1;                        // 16384 (as float)

    float* ws    = (float*)d_ws;
    float* cn    = ws;                                // 524288
    float* zn    = cn + (size_t)P_DIM * C_DIM;        // 1048576
    float* pval  = zn + (size_t)M_TOT * C_DIM;        // 262144
    int*   pidx  = (int*)(pval + (size_t)M_TOT * NCHUNK); // 262144
    int*   idxi  = (int*)((float*)pidx + (size_t)M_TOT * NCHUNK); // 16384
    float* wT    = (float*)idxi + M_TOT;              // 49152
    float* lossp = wT + (size_t)C_DIM * F_DIM;        // 4096

    k_norm_cb<<<P_DIM / 4, 256, 0, stream>>>(cb, cn);
    k_transpose_wout<<<(C_DIM * F_DIM) / 256, 256, 0, stream>>>(w_out, wT);
    k_proj<<<M_TOT / B_ROWS, 256, 0, stream>>>(z, w_in, zn);

    dim3 gC(M_TOT / 64, NCHUNK);
    k_argmax<<<gC, 64, 0, stream>>>(zn, cn, pval, pidx);
    k_merge<<<M_TOT / 256, 256, 0, stream>>>(pval, pidx, idxi, idxO);

    dim3 gD(M_TOT / D_ROWS, F_DIM / 64);
    k_out<<<gD, 256, 0, stream>>>(idxi, cn, wT, out);

    k_loss<<<M_TOT / 4, 256, 0, stream>>>(zn, cn, idxi, lossp);
    k_loss_final<<<1, 256, 0, stream>>>(lossp, lossO);
}